// Round 3
// baseline (297.496 us; speedup 1.0000x reference)
//
#include <hip/hip_runtime.h>
#include <hip/hip_bf16.h>
#include <hip/hip_cooperative_groups.h>

namespace cg = cooperative_groups;

#define N_NODES 100000
#define N_EDGES 250000
#define EMB 32
#define TYPES 16
#define R2 100          // num relations
#define SB 1024
#define NB ((N_EDGES + SB - 1) / SB)    // 245
#define CAP 4096        // per-relation slot capacity (counts ~2500±50)
#define CAPD 16         // per-node slot capacity (max degree ~14; rank clamped)
#define S1 64           // stripes per relation, classic fallback layer 1
#define S2 64           // stripes per relation, classic fallback layer 2
#define GRID 256        // cooperative grid: 1 block per CU
#define TPB 1024        // 16 waves per block
#define SJ 40           // stripes per relation in mega path (100*40 = 4000 <= 4096 waves)

typedef __attribute__((ext_vector_type(8))) short short8;
typedef __attribute__((ext_vector_type(4))) float f32x4;

// fp32 -> bf16 bits, round-to-nearest-even
__device__ __forceinline__ unsigned short f2bf_u(float f) {
    unsigned u = __float_as_uint(f);
    u = (u + 0x7fffu + ((u >> 16) & 1u)) >> 16;
    return (unsigned short)u;
}
// unpack bf16 pair from u32
__device__ __forceinline__ float bfl(unsigned u) { return __uint_as_float(u << 16); }
__device__ __forceinline__ float bfh(unsigned u) { return __uint_as_float(u & 0xffff0000u); }

struct Ptrs {
    const int *etype, *edge_src, *edge_dst, *src_ids;
    const float *entity, *W1, *W2, *lw, *lb;
    int *rcnt, *dcnt;
    unsigned short *ent_bf, *pw1, *pw2;
    uint2 *epack;               // 8B/edge: {sid | pd_lo15<<17, s | pd_hi6<<17}
    unsigned int *msg1, *h1bf, *msg2;
    float *out;
};

// ---------------------------------------------------------------------------
// Phase 1 chunk: b < NB -> edge chunk (hist ranks + dst ranks + epack scatter
// + entity bf16 convert); b >= NB -> W1/W2 bf16 fragment packing.
__device__ __forceinline__ void do_pass1_chunk(const Ptrs& P, int b, int t,
                                               int* lh, int* lbase) {
    if (b < NB) {
        if (t < R2) lh[t] = 0;
        __syncthreads();
        int e = b * SB + t;
        int r = 0, lrank = 0, pd = 0, s = 0, sid = 0;
        bool valid = e < N_EDGES;
        if (valid) {
            r = P.etype[e];
            lrank = atomicAdd(&lh[r], 1);           // rank within (chunk, rel)
            int d = P.edge_dst[e];
            int drank = atomicAdd(&P.dcnt[d], 1);   // global dst rank (order free)
            if (drank > CAPD - 1) drank = CAPD - 1; // clamp (dup slot overwrite ok)
            pd = (d << 4) | drank;                  // final msg slot, 21 bits
            s = P.edge_src[e];
            sid = P.src_ids[s];
        }
        // fused entity fp32 -> bf16 (2 threads per row, coalesced)
        if (e < 2 * N_NODES) {
            int node = e >> 1, half = e & 1;
            const float4* src = (const float4*)(P.entity + (size_t)node * EMB + half * 16);
            ushort4* dst = (ushort4*)(P.ent_bf + (size_t)node * EMB + half * 16);
#pragma unroll
            for (int i = 0; i < 4; ++i) {
                float4 v = src[i];
                ushort4 o = { f2bf_u(v.x), f2bf_u(v.y), f2bf_u(v.z), f2bf_u(v.w) };
                dst[i] = o;
            }
        }
        __syncthreads();
        if (t < R2) {
            int c = lh[t];
            lbase[t] = c ? atomicAdd(&P.rcnt[t], c) : 0;
        }
        __syncthreads();
        if (valid) {
            uint2 v = { (unsigned)sid | (((unsigned)pd & 0x7FFFu) << 17),
                        (unsigned)s   | (((unsigned)pd >> 15) << 17) };
            P.epack[((size_t)r << 12) + lbase[r] + lrank] = v;
        }
    } else {
        int r = b - NB;
        // pack W1: b0 slot j<8 -> col 2n, b1 slot j>=8 -> col 2n+1; k = q*8+j
        const float* Wr1 = P.W1 + (size_t)r * (EMB * EMB);
        {
            int l = t >> 4, j = t & 15;
            int n = l & 15, q = l >> 4;
            int k = q * 8 + (j & 7);
            int col = (j < 8) ? (2 * n) : (2 * n + 1);
            P.pw1[(size_t)r * 1024 + t] = f2bf_u(Wr1[k * EMB + col]);
        }
        if (t < 512) {
            const float* Wr2 = P.W2 + (size_t)r * (EMB * TYPES);
            int l = t >> 3, j = t & 7;
            int n = l & 15, q = l >> 4;
            int k = q * 8 + j;
            P.pw2[(size_t)r * 512 + t] = f2bf_u(Wr2[k * TYPES + n]);
        }
    }
}

// ---------------------------------------------------------------------------
// Layer 1 wave job: relation r, stripe over its 16-row tiles.
__device__ __forceinline__ void do_layer1_wave(const Ptrs& P, int r, int stripe,
                                               int S, int lane) {
    int cnt = P.rcnt[r];
    int nT = (cnt + 15) >> 4;
    int n = lane & 15, q = lane >> 4;
    const unsigned short* pw = P.pw1 + (size_t)r * 1024;
    short8 b0 = *(const short8*)(pw + lane * 16);
    short8 b1 = *(const short8*)(pw + lane * 16 + 8);
    const uint2* ep = P.epack + ((size_t)r << 12);
    for (int g = stripe; g < nT; g += S) {
        int base = g * 16;
        int cl = cnt - base;
        int me = n < cl ? n : cl - 1;
        uint2 E = ep[base + me];
        int sid = (int)(E.x & 0x1FFFFu);
        int pd  = (int)((E.x >> 17) | ((E.y >> 17) << 15));
        short8 a = *(const short8*)(P.ent_bf + (size_t)sid * EMB + q * 8);
        f32x4 c0 = {0.f,0.f,0.f,0.f}, c1 = {0.f,0.f,0.f,0.f};
        c0 = __builtin_amdgcn_mfma_f32_16x16x32_bf16(a, b0, c0, 0, 0, 0);
        c1 = __builtin_amdgcn_mfma_f32_16x16x32_bf16(a, b1, c1, 0, 0, 0);
#pragma unroll
        for (int i = 0; i < 4; ++i) {
            int row = q * 4 + i;
            int p = __shfl(pd, row);            // lanes 0..15 hold rows 0..15
            if (row < cl) {
                unsigned w = (unsigned)f2bf_u(c0[i]) | ((unsigned)f2bf_u(c1[i]) << 16);
                P.msg1[(size_t)p * 16 + n] = w; // cols (2n, 2n+1), coalesced
            }
        }
    }
}

// ---------------------------------------------------------------------------
// Reduce1 item: segmented mean + relu -> h1 bf16x2.
__device__ __forceinline__ void do_reduce1_item(const Ptrs& P, int ti) {
    int nn = ti >> 4, cp = ti & 15;
    int cnt = P.dcnt[nn];
    int km = cnt < CAPD ? cnt : CAPD;
    int s = nn << 4;
    float sx = 0.f, sy = 0.f;
    for (int k = 0; k < km; ++k) {
        unsigned v = P.msg1[(size_t)(s + k) * 16 + cp];   // row = 16 u32
        sx += bfl(v); sy += bfh(v);
    }
    float inv = 1.0f / fmaxf((float)cnt, 1.0f);
    unsigned lo = f2bf_u(fmaxf(sx * inv, 0.f));
    unsigned hi = f2bf_u(fmaxf(sy * inv, 0.f));
    P.h1bf[ti] = lo | (hi << 16);
}

// ---------------------------------------------------------------------------
// Layer 2 wave job.
__device__ __forceinline__ void do_layer2_wave(const Ptrs& P, int r, int stripe,
                                               int S, int lane) {
    int cnt = P.rcnt[r];
    int nT = (cnt + 15) >> 4;
    int n = lane & 15, q = lane >> 4;
    short8 b = *(const short8*)(P.pw2 + (size_t)r * 512 + lane * 8);
    const uint2* ep = P.epack + ((size_t)r << 12);
    const unsigned short* h1 = (const unsigned short*)P.h1bf;
    for (int g = stripe; g < nT; g += S) {
        int base = g * 16;
        int cl = cnt - base;
        int me = n < cl ? n : cl - 1;
        uint2 E = ep[base + me];
        int s  = (int)(E.y & 0x1FFFFu);
        int pd = (int)((E.x >> 17) | ((E.y >> 17) << 15));
        short8 a = *(const short8*)(h1 + (size_t)s * EMB + q * 8);
        f32x4 c = {0.f,0.f,0.f,0.f};
        c = __builtin_amdgcn_mfma_f32_16x16x32_bf16(a, b, c, 0, 0, 0);
#pragma unroll
        for (int i = 0; i < 4; ++i) {
            int row = q * 4 + i;
            int p = __shfl(pd, row);
            unsigned myb = (unsigned)f2bf_u(c[i]);
            unsigned ob  = (unsigned)__shfl_xor((int)myb, 1);
            if (row < cl && !(n & 1)) {
                P.msg2[(size_t)p * 8 + (n >> 1)] = myb | (ob << 16);  // cols (n, n+1)
            }
        }
    }
}

// ---------------------------------------------------------------------------
// Reduce2 + PonderNet head, writes final fp32 output.
__device__ __forceinline__ void do_reduce2_item(const Ptrs& P, int nn) {
    int cnt = P.dcnt[nn];
    int km = cnt < CAPD ? cnt : CAPD;
    int s = nn << 4;
    float h[TYPES];
#pragma unroll
    for (int j = 0; j < TYPES; ++j) h[j] = 0.f;
    for (int k = 0; k < km; ++k) {
        const uint4* row = (const uint4*)(P.msg2 + (size_t)(s + k) * 8);
        uint4 A = row[0], B = row[1];
        h[0] += bfl(A.x);  h[1] += bfh(A.x);  h[2] += bfl(A.y);  h[3] += bfh(A.y);
        h[4] += bfl(A.z);  h[5] += bfh(A.z);  h[6] += bfl(A.w);  h[7] += bfh(A.w);
        h[8] += bfl(B.x);  h[9] += bfh(B.x);  h[10] += bfl(B.y); h[11] += bfh(B.y);
        h[12] += bfl(B.z); h[13] += bfh(B.z); h[14] += bfl(B.w); h[15] += bfh(B.w);
    }
    float inv = 1.0f / fmaxf((float)cnt, 1.0f);
    float dot = 0.f;
#pragma unroll
    for (int j = 0; j < TYPES; ++j) { h[j] *= inv; dot += h[j] * P.lw[j]; }
    dot += P.lb[0];
    float lam = 1.0f / (1.0f + expf(-dot));

    float4* y0 = (float4*)(P.out + (size_t)nn * TYPES);
    float4* y1 = (float4*)(P.out + (size_t)N_NODES * TYPES + (size_t)nn * TYPES);
#pragma unroll
    for (int j = 0; j < 4; ++j) {
        float4 v = { h[4*j], h[4*j+1], h[4*j+2], h[4*j+3] };
        y0[j] = v; y1[j] = v;
    }
    P.out[(size_t)2 * N_NODES * TYPES + nn] = lam;
    P.out[(size_t)2 * N_NODES * TYPES + N_NODES + nn] = 1.0f - lam;
}

// ---------------------------------------------------------------------------
// The cooperative mega-kernel: all phases, grid.sync() between them.
__global__ __launch_bounds__(TPB, 4) void mega_kernel(Ptrs P) {
    cg::grid_group grid = cg::this_grid();
    __shared__ int lh[R2], lbase[R2];
    const int t = threadIdx.x, blk = blockIdx.x, nblk = gridDim.x;
    const int gtid = blk * TPB + t;
    const int nthr = nblk * TPB;

    // Phase Z: zero dcnt + rcnt (replaces memset dispatch)
    if (gtid < N_NODES) P.dcnt[gtid] = 0;
    else if (gtid < N_NODES + 128) P.rcnt[gtid - N_NODES] = 0;
    grid.sync();

    // Phase 1: hist/scatter/convert + W pack (345 chunks over 256 blocks)
    for (int b = blk; b < NB + R2; b += nblk)
        do_pass1_chunk(P, b, t, lh, lbase);
    grid.sync();

    // Phase 2: layer 1 (4000 wave jobs over 4096 wave slots)
    {
        int wslot = (blk << 4) | (t >> 6);
        int lane = t & 63;
        if (wslot < R2 * SJ)
            do_layer1_wave(P, wslot % R2, wslot / R2, SJ, lane);
    }
    grid.sync();

    // Phase 3: reduce 1 (1.6M items, grid-stride)
    for (int i = gtid; i < N_NODES * 16; i += nthr)
        do_reduce1_item(P, i);
    grid.sync();

    // Phase 4: layer 2
    {
        int wslot = (blk << 4) | (t >> 6);
        int lane = t & 63;
        if (wslot < R2 * SJ)
            do_layer2_wave(P, wslot % R2, wslot / R2, SJ, lane);
    }
    grid.sync();

    // Phase 5: reduce 2 + head
    if (gtid < N_NODES) do_reduce2_item(P, gtid);
}

// ---------------------------------------------------------------------------
// Classic fallback kernels (used only if cooperative launch is rejected).
__global__ __launch_bounds__(SB) void k_pass1(Ptrs P) {
    __shared__ int lh[R2], lbase[R2];
    do_pass1_chunk(P, blockIdx.x, threadIdx.x, lh, lbase);
}
__global__ __launch_bounds__(64) void k_layer1(Ptrs P) {
    do_layer1_wave(P, blockIdx.x % R2, blockIdx.x / R2, S1, threadIdx.x);
}
__global__ void k_reduce1(Ptrs P) {
    int i = blockIdx.x * blockDim.x + threadIdx.x;
    if (i < N_NODES * 16) do_reduce1_item(P, i);
}
__global__ __launch_bounds__(64) void k_layer2(Ptrs P) {
    do_layer2_wave(P, blockIdx.x % R2, blockIdx.x / R2, S2, threadIdx.x);
}
__global__ void k_reduce2(Ptrs P) {
    int nn = blockIdx.x * blockDim.x + threadIdx.x;
    if (nn < N_NODES) do_reduce2_item(P, nn);
}

// ---------------------------------------------------------------------------
extern "C" void kernel_launch(void* const* d_in, const int* in_sizes, int n_in,
                              void* d_out, int out_size, void* d_ws, size_t ws_size,
                              hipStream_t stream) {
    unsigned int* W = (unsigned int*)d_ws;
    Ptrs P;
    P.etype    = (const int*)d_in[8];
    P.edge_src = (const int*)d_in[6];
    P.edge_dst = (const int*)d_in[7];
    P.src_ids  = (const int*)d_in[5];
    P.entity   = (const float*)d_in[0];
    P.W1       = (const float*)d_in[1];
    P.W2       = (const float*)d_in[2];
    P.lw       = (const float*)d_in[3];
    P.lb       = (const float*)d_in[4];
    P.out      = (float*)d_out;
    // ws layout (u32 units, all 16B aligned)
    P.dcnt   = (int*)(W + 0);              // 100000  (zeroed in-kernel / memset)
    P.rcnt   = (int*)(W + 100000);         // 128
    P.epack  = (uint2*)(W + 100128);       // R2*CAP uint2 = 819,200 u32
    P.ent_bf = (unsigned short*)(W + 919328);   // 1.6M u32
    P.pw1    = (unsigned short*)(W + 2519328);  // 51,200 u32
    P.pw2    = (unsigned short*)(W + 2570528);  // 25,600 u32
    P.h1bf   = W + 2596128;                // 1.6M u32
    P.msg1   = W + 4196128;                // N_NODES*CAPD*16 u32 = 25.6M u32
    P.msg2   = W + 29796128;               // N_NODES*CAPD*8  u32 = 12.8M u32
    // total: 42,596,128 u32 = 170.4 MB

    void* args[] = { (void*)&P };
    hipError_t e = hipLaunchCooperativeKernel(
        reinterpret_cast<const void*>(&mega_kernel),
        dim3(GRID), dim3(TPB), args, 0, stream);

    if (e != hipSuccess) {
        // Fallback: classic 6-dispatch path (proven in round 2).
        (void)hipMemsetAsync(d_ws, 0, 100128 * sizeof(int), stream);
        k_pass1<<<NB + R2, SB, 0, stream>>>(P);
        k_layer1<<<R2 * S1, 64, 0, stream>>>(P);
        k_reduce1<<<(N_NODES * 16 + 255) / 256, 256, 0, stream>>>(P);
        k_layer2<<<R2 * S2, 64, 0, stream>>>(P);
        k_reduce2<<<(N_NODES + 255) / 256, 256, 0, stream>>>(P);
    }
}

// Round 4
// 131.145 us; speedup vs baseline: 2.2685x; 2.2685x over previous
//
#include <hip/hip_runtime.h>
#include <hip/hip_bf16.h>

#define N_NODES 100000
#define N_EDGES 250000
#define EMB 32
#define TYPES 16
#define R2 100          // num relations
#define SB 1024
#define NB ((N_EDGES + SB - 1) / SB)    // 245
#define CAP 4096        // per-relation slot capacity (counts ~2500±50)
#define CAPD 16         // per-node slot capacity (Poisson(2.5): P(deg>16) ~ 1e-10)
#define S1 64           // stripes per relation, layer 1
#define S2 64           // stripes per relation, layer 2

typedef __attribute__((ext_vector_type(8))) short short8;
typedef __attribute__((ext_vector_type(4))) float f32x4;

// fp32 -> bf16 bits, round-to-nearest-even
__device__ __forceinline__ unsigned short f2bf_u(float f) {
    unsigned u = __float_as_uint(f);
    u = (u + 0x7fffu + ((u >> 16) & 1u)) >> 16;
    return (unsigned short)u;
}
// unpack bf16 pair from u32
__device__ __forceinline__ float bfl(unsigned u) { return __uint_as_float(u << 16); }
__device__ __forceinline__ float bfh(unsigned u) { return __uint_as_float(u & 0xffff0000u); }

// ---------------------------------------------------------------------------
// Pass 1: blocks [0,NB) = edge scatter (LDS relation ranks + one global
// atomicAdd per (block,rel); dst slot = (d<<4)|drank via dcnt atomic).
// epack = 8B/edge: {sid | pd_lo15<<17, s | pd_hi6<<17}.
// Blocks [NB,NB+R2) = W1/W2 bf16 fragment packing (pw1 = column pairs).
__global__ __launch_bounds__(SB) void pass1_kernel(
        const int* __restrict__ etype, const int* __restrict__ edge_src,
        const int* __restrict__ edge_dst, const int* __restrict__ src_ids,
        const float* __restrict__ W1, const float* __restrict__ W2,
        int* __restrict__ rcnt, int* __restrict__ dcnt,
        unsigned short* __restrict__ pw1, unsigned short* __restrict__ pw2,
        uint2* __restrict__ epack) {
    int t = threadIdx.x, b = blockIdx.x;
    if (b < NB) {
        __shared__ int lh[R2];
        __shared__ int lbase[R2];
        if (t < R2) lh[t] = 0;
        __syncthreads();
        int e = b * SB + t;
        int r = 0, lrank = 0, pd = 0, s = 0, sid = 0;
        bool valid = e < N_EDGES;
        if (valid) {
            r = etype[e];
            lrank = atomicAdd(&lh[r], 1);           // rank within (chunk, rel)
            int d = edge_dst[e];
            int drank = atomicAdd(&dcnt[d], 1);     // global dst rank (order free)
            if (drank > CAPD - 1) drank = CAPD - 1; // safety clamp
            pd = (d << 4) | drank;                  // final msg slot, 21 bits
            s = edge_src[e];
            sid = src_ids[s];
        }
        __syncthreads();
        if (t < R2) {
            int c = lh[t];
            lbase[t] = c ? atomicAdd(&rcnt[t], c) : 0;
        }
        __syncthreads();
        if (valid) {
            uint2 v = { (unsigned)sid | (((unsigned)pd & 0x7FFFu) << 17),
                        (unsigned)s   | (((unsigned)pd >> 15) << 17) };
            epack[((size_t)r << 12) + lbase[r] + lrank] = v;
        }
    } else {
        int r = b - NB;
        // pack W1: b0 slot j<8 -> col 2n, b1 slot j>=8 -> col 2n+1; k = q*8+j
        const float* Wr1 = W1 + (size_t)r * (EMB * EMB);
        {
            int l = t >> 4, j = t & 15;
            int n = l & 15, q = l >> 4;
            int k = q * 8 + (j & 7);
            int col = (j < 8) ? (2 * n) : (2 * n + 1);
            pw1[(size_t)r * 1024 + t] = f2bf_u(Wr1[k * EMB + col]);
        }
        if (t < 512) {
            const float* Wr2 = W2 + (size_t)r * (EMB * TYPES);
            int l = t >> 3, j = t & 7;
            int n = l & 15, q = l >> 4;
            int k = q * 8 + j;
            pw2[(size_t)r * 512 + t] = f2bf_u(Wr2[k * TYPES + n]);
        }
    }
}

// ---------------------------------------------------------------------------
// Layer 1: gather entity rows DIRECTLY in fp32 (32B/lane), convert to bf16
// in-register, 2 MFMA/tile (cols 2n/2n+1), coalesced u32 stores to msg1
// at direct slot pd (no dstart indirection anywhere).
__global__ __launch_bounds__(64) void layer1_kernel(
        const float* __restrict__ entity,
        const unsigned short* __restrict__ pw1,
        const int* __restrict__ rcnt,
        const uint2* __restrict__ epack,
        unsigned int* __restrict__ msg1) {
    int r = blockIdx.x % R2, stripe = blockIdx.x / R2;
    int cnt = rcnt[r];
    int nT = (cnt + 15) >> 4;
    int lane = threadIdx.x;
    int n = lane & 15, q = lane >> 4;
    const unsigned short* pw = pw1 + (size_t)r * 1024;
    short8 b0 = *(const short8*)(pw + lane * 16);
    short8 b1 = *(const short8*)(pw + lane * 16 + 8);
    const uint2* ep = epack + ((size_t)r << 12);
    for (int g = stripe; g < nT; g += S1) {
        int base = g * 16;
        int cl = cnt - base;
        int me = n < cl ? n : cl - 1;
        uint2 E = ep[base + me];
        int sid = (int)(E.x & 0x1FFFFu);
        int pd  = (int)((E.x >> 17) | ((E.y >> 17) << 15));
        const float4* ar = (const float4*)(entity + (size_t)sid * EMB + q * 8);
        float4 v0 = ar[0], v1 = ar[1];
        short8 a;
        a[0] = (short)f2bf_u(v0.x); a[1] = (short)f2bf_u(v0.y);
        a[2] = (short)f2bf_u(v0.z); a[3] = (short)f2bf_u(v0.w);
        a[4] = (short)f2bf_u(v1.x); a[5] = (short)f2bf_u(v1.y);
        a[6] = (short)f2bf_u(v1.z); a[7] = (short)f2bf_u(v1.w);
        f32x4 c0 = {0.f,0.f,0.f,0.f}, c1 = {0.f,0.f,0.f,0.f};
        c0 = __builtin_amdgcn_mfma_f32_16x16x32_bf16(a, b0, c0, 0, 0, 0);
        c1 = __builtin_amdgcn_mfma_f32_16x16x32_bf16(a, b1, c1, 0, 0, 0);
#pragma unroll
        for (int i = 0; i < 4; ++i) {
            int row = q * 4 + i;
            int p = __shfl(pd, row);            // lanes 0..15 hold rows 0..15
            if (row < cl) {
                unsigned w = (unsigned)f2bf_u(c0[i]) | ((unsigned)f2bf_u(c1[i]) << 16);
                msg1[(size_t)p * 16 + n] = w;   // cols (2n, 2n+1), coalesced
            }
        }
    }
}

// ---------------------------------------------------------------------------
// Segmented mean + relu -> h1 in bf16 (u32 = 2 cols). Sums in fp32.
// Direct layout: node nn's messages at rows [nn*16, nn*16+cnt) -> contiguous.
__global__ void reduce1_kernel(const unsigned int* __restrict__ msg1,
                               const int* __restrict__ dcnt,
                               unsigned int* __restrict__ h1bf) {
    int t = blockIdx.x * blockDim.x + threadIdx.x;   // over N_NODES*16
    if (t >= N_NODES * 16) return;
    int nn = t >> 4, cp = t & 15;
    int cnt = dcnt[nn];
    int km = cnt < CAPD ? cnt : CAPD;
    int s = nn << 4;
    float sx = 0.f, sy = 0.f;
    for (int k = 0; k < km; ++k) {
        unsigned v = msg1[(size_t)(s + k) * 16 + cp];   // row = 16 u32
        sx += bfl(v); sy += bfh(v);
    }
    float inv = 1.0f / fmaxf((float)cnt, 1.0f);
    unsigned lo = f2bf_u(fmaxf(sx * inv, 0.f));
    unsigned hi = f2bf_u(fmaxf(sy * inv, 0.f));
    h1bf[t] = lo | (hi << 16);
}

// ---------------------------------------------------------------------------
// Layer 2: gather bf16 h1 rows (16B/lane), 1 MFMA/tile; column pairing via
// shfl_xor -> one u32 store per even lane-row.
__global__ __launch_bounds__(64) void layer2_kernel(
        const unsigned short* __restrict__ h1bf,
        const unsigned short* __restrict__ pw2,
        const int* __restrict__ rcnt,
        const uint2* __restrict__ epack,
        unsigned int* __restrict__ msg2) {
    int r = blockIdx.x % R2, stripe = blockIdx.x / R2;
    int cnt = rcnt[r];
    int nT = (cnt + 15) >> 4;
    int lane = threadIdx.x;
    int n = lane & 15, q = lane >> 4;
    short8 b = *(const short8*)(pw2 + (size_t)r * 512 + lane * 8);
    const uint2* ep = epack + ((size_t)r << 12);
    for (int g = stripe; g < nT; g += S2) {
        int base = g * 16;
        int cl = cnt - base;
        int me = n < cl ? n : cl - 1;
        uint2 E = ep[base + me];
        int s  = (int)(E.y & 0x1FFFFu);
        int pd = (int)((E.x >> 17) | ((E.y >> 17) << 15));
        short8 a = *(const short8*)(h1bf + (size_t)s * EMB + q * 8);
        f32x4 c = {0.f,0.f,0.f,0.f};
        c = __builtin_amdgcn_mfma_f32_16x16x32_bf16(a, b, c, 0, 0, 0);
#pragma unroll
        for (int i = 0; i < 4; ++i) {
            int row = q * 4 + i;
            int p = __shfl(pd, row);
            unsigned myb = (unsigned)f2bf_u(c[i]);
            unsigned ob  = (unsigned)__shfl_xor((int)myb, 1);
            if (row < cl && !(n & 1)) {
                msg2[(size_t)p * 8 + (n >> 1)] = myb | (ob << 16);  // cols (n, n+1)
            }
        }
    }
}

// ---------------------------------------------------------------------------
// Segmented mean + PonderNet head, fused; writes final fp32 output.
__global__ void reduce2_head_kernel(const unsigned int* __restrict__ msg2,
                                    const int* __restrict__ dcnt,
                                    const float* __restrict__ lw,
                                    const float* __restrict__ lb,
                                    float* __restrict__ out) {
    int nn = blockIdx.x * blockDim.x + threadIdx.x;
    if (nn >= N_NODES) return;
    int cnt = dcnt[nn];
    int km = cnt < CAPD ? cnt : CAPD;
    int s = nn << 4;
    float h[TYPES];
#pragma unroll
    for (int j = 0; j < TYPES; ++j) h[j] = 0.f;
    for (int k = 0; k < km; ++k) {
        const uint4* row = (const uint4*)(msg2 + (size_t)(s + k) * 8);  // 16 bf16
        uint4 A = row[0], B = row[1];
        h[0] += bfl(A.x);  h[1] += bfh(A.x);  h[2] += bfl(A.y);  h[3] += bfh(A.y);
        h[4] += bfl(A.z);  h[5] += bfh(A.z);  h[6] += bfl(A.w);  h[7] += bfh(A.w);
        h[8] += bfl(B.x);  h[9] += bfh(B.x);  h[10] += bfl(B.y); h[11] += bfh(B.y);
        h[12] += bfl(B.z); h[13] += bfh(B.z); h[14] += bfl(B.w); h[15] += bfh(B.w);
    }
    float inv = 1.0f / fmaxf((float)cnt, 1.0f);
    float dot = 0.f;
#pragma unroll
    for (int j = 0; j < TYPES; ++j) { h[j] *= inv; dot += h[j] * lw[j]; }
    dot += lb[0];
    float lam = 1.0f / (1.0f + expf(-dot));

    float4* y0 = (float4*)(out + (size_t)nn * TYPES);
    float4* y1 = (float4*)(out + (size_t)N_NODES * TYPES + (size_t)nn * TYPES);
#pragma unroll
    for (int j = 0; j < 4; ++j) {
        float4 v = { h[4*j], h[4*j+1], h[4*j+2], h[4*j+3] };
        y0[j] = v; y1[j] = v;
    }
    out[(size_t)2 * N_NODES * TYPES + nn] = lam;
    out[(size_t)2 * N_NODES * TYPES + N_NODES + nn] = 1.0f - lam;
}

// ---------------------------------------------------------------------------
extern "C" void kernel_launch(void* const* d_in, const int* in_sizes, int n_in,
                              void* d_out, int out_size, void* d_ws, size_t ws_size,
                              hipStream_t stream) {
    const float* entity = (const float*)d_in[0];
    const float* W1     = (const float*)d_in[1];
    const float* W2     = (const float*)d_in[2];
    const float* lw     = (const float*)d_in[3];
    const float* lb     = (const float*)d_in[4];
    const int* src_ids  = (const int*)d_in[5];
    const int* edge_src = (const int*)d_in[6];
    const int* edge_dst = (const int*)d_in[7];
    const int* etype    = (const int*)d_in[8];
    float* out = (float*)d_out;

    // ws layout (u32 units, all 16B aligned)
    unsigned int* W = (unsigned int*)d_ws;
    int* dcnt   = (int*)(W + 0);              // 100000  (zeroed)
    int* rcnt   = (int*)(W + 100000);         // 128     (zeroed)
    uint2* epack = (uint2*)(W + 100128);      // R2*CAP uint2 = 819,200 u32
    unsigned short* pw1 = (unsigned short*)(W + 919328);  // 51,200 u32
    unsigned short* pw2 = (unsigned short*)(W + 970528);  // 25,600 u32
    unsigned int* h1bf  = W + 996128;         // 1.6M u32
    unsigned int* msg1  = W + 2596128;        // N_NODES*CAPD*16 u32 = 25.6M u32
    unsigned int* msg2  = W + 28196128;       // N_NODES*CAPD*8  u32 = 12.8M u32
    // total: 40,996,128 u32 = 164 MB

    (void)hipMemsetAsync(d_ws, 0, 100128 * sizeof(int), stream);  // dcnt+rcnt

    pass1_kernel<<<NB + R2, SB, 0, stream>>>(etype, edge_src, edge_dst, src_ids,
                                             W1, W2, rcnt, dcnt, pw1, pw2, epack);
    layer1_kernel<<<R2 * S1, 64, 0, stream>>>(entity, pw1, rcnt, epack, msg1);
    reduce1_kernel<<<(N_NODES * 16 + 255) / 256, 256, 0, stream>>>(msg1, dcnt, h1bf);
    layer2_kernel<<<R2 * S2, 64, 0, stream>>>((const unsigned short*)h1bf, pw2,
                                              rcnt, epack, msg2);
    reduce2_head_kernel<<<(N_NODES + 255) / 256, 256, 0, stream>>>(
        msg2, dcnt, lw, lb, out);
}